// Round 3
// baseline (472.241 us; speedup 1.0000x reference)
//
#include <hip/hip_runtime.h>
#include <stdint.h>

#define IN_F  4096
#define OUT_F 4096

typedef unsigned short u16;
typedef __attribute__((ext_vector_type(8))) short bf16x8;
typedef __attribute__((ext_vector_type(4))) float f32x4;

__device__ __forceinline__ u16 f2bf(float f) {
    union { float f; unsigned u; } c; c.f = f;
    unsigned u = c.u;
    return (u16)((u + 0x7FFFu + ((u >> 16) & 1u)) >> 16);
}
__device__ __forceinline__ float bf2f(u16 h) {
    union { unsigned u; float f; } c; c.u = ((unsigned)h) << 16;
    return c.f;
}

// async global->LDS, 16B per lane. LDS dest is wave-uniform base + lane*16.
__device__ __forceinline__ void load_lds16(const void* g, void* l) {
    unsigned loff = (unsigned)(uintptr_t)l;
    loff = (unsigned)__builtin_amdgcn_readfirstlane((int)loff);
    __builtin_amdgcn_global_load_lds(
        (const __attribute__((address_space(1))) void*)(uintptr_t)g,
        (__attribute__((address_space(3))) void*)(uintptr_t)loff,
        16, 0, 0);
}

// ---------------------------------------------------------------------------
// Kernel 1: MERGED prep kernel.
//   blocks [0, 1024):      fused dequant + CSR outliers -> W bf16 [OUT][IN]
//   blocks [1024, 17408):  x fp32 -> bf16 (RNE), 8 floats/thread
// ---------------------------------------------------------------------------
#define DQ_O 64
#define DQ_I 256   // 32 packed words
#define DQ_BLOCKS ((IN_F / DQ_I) * (OUT_F / DQ_O))   // 1024

__global__ __launch_bounds__(256) void prep_k(const int* __restrict__ qw,
                                              const float* __restrict__ lut,
                                              const int* __restrict__ rows,
                                              const int* __restrict__ cols,
                                              const float* __restrict__ vals,
                                              u16* __restrict__ W,
                                              const float4* __restrict__ x,
                                              u16* __restrict__ xb) {
    __shared__ __align__(16) u16 sW[DQ_O * DQ_I];   // 32 KB
    __shared__ u16 slut[DQ_O * 18];                 // padded stride 18

    const int tid = threadIdx.x;

    if (blockIdx.x >= DQ_BLOCKS) {
        // ---- cvtx part: pure streaming convert
        const size_t i = (size_t)(blockIdx.x - DQ_BLOCKS) * 256 + tid;
        const float4 a = x[2 * i];
        const float4 b = x[2 * i + 1];
        union { u16 h[8]; uint4 v; } u;
        u.h[0] = f2bf(a.x); u.h[1] = f2bf(a.y); u.h[2] = f2bf(a.z); u.h[3] = f2bf(a.w);
        u.h[4] = f2bf(b.x); u.h[5] = f2bf(b.y); u.h[6] = f2bf(b.z); u.h[7] = f2bf(b.w);
        *(uint4*)(xb + i * 8) = u.v;
        return;
    }

    // ---- dequant part
    const int o0 = (blockIdx.x >> 4) * DQ_O;          // 64 o-blocks
    const int i0 = (blockIdx.x & 15) * DQ_I;          // 16 i-blocks
    const int p0 = i0 >> 3;

    {
        const int idx = tid * 4;
        const float4 v = *(const float4*)(lut + (size_t)o0 * 16 + idx);
        u16* d = slut + (idx >> 4) * 18 + (idx & 15);
        d[0] = f2bf(v.x); d[1] = f2bf(v.y); d[2] = f2bf(v.z); d[3] = f2bf(v.w);
    }
    __syncthreads();

    const int o_l = tid & 63;
    const int swz = o_l & 31;
#pragma unroll
    for (int it = 0; it < 8; ++it) {
        const int p = (tid >> 6) + it * 4;                       // 0..31
        const unsigned w = (unsigned)qw[(size_t)(p0 + p) * OUT_F + (o0 + o_l)];
        union { u16 h[8]; uint4 v; } u;
#pragma unroll
        for (int j = 0; j < 8; ++j)
            u.h[j] = slut[o_l * 18 + ((w >> (4 * j)) & 15u)];
        *(uint4*)(sW + o_l * DQ_I + ((p ^ swz) << 3)) = u.v;
    }
    __syncthreads();

    // CSR outliers: one thread per o-row, 4x load batching, serial apply.
    if (tid < DQ_O) {
        const int s = rows[o0 + tid], e = rows[o0 + tid + 1];
        int k = s;
#define APPLY(CJ, VV) do {                                                  \
        const unsigned j_ = (unsigned)((CJ) - i0);                          \
        if (j_ < DQ_I) {                                                    \
            u16* p16 = sW + tid * DQ_I + (((j_ >> 3) ^ swz) << 3) + (j_ & 7); \
            *p16 = f2bf(bf2f(*p16) + (VV));                                 \
        } } while (0)
        for (; k + 4 <= e; k += 4) {
            const int c0 = cols[k], c1 = cols[k + 1], c2 = cols[k + 2], c3 = cols[k + 3];
            const float v0 = vals[k], v1 = vals[k + 1], v2 = vals[k + 2], v3 = vals[k + 3];
            APPLY(c0, v0); APPLY(c1, v1); APPLY(c2, v2); APPLY(c3, v3);
        }
        for (; k < e; ++k) APPLY(cols[k], vals[k]);
#undef APPLY
    }
    __syncthreads();

    const int ch = tid & 31;
#pragma unroll
    for (int it = 0; it < 8; ++it) {
        const int r = (tid >> 5) + it * 8;                       // 0..63
        *(uint4*)(W + (size_t)(o0 + r) * IN_F + i0 + ch * 8) =
            *(const uint4*)(sW + r * DQ_I + ((ch ^ (r & 31)) << 3));
    }
}

// ---------------------------------------------------------------------------
// Kernel 2: GEMM  y[M][N] = A[M][K] * B[N][K]^T + bias   (A,B bf16; y fp32)
// 256x256 tile, 8 waves (2M x 4N, each 128x64), 8-phase schedule v3:
//   - 4-slot LDS ring per operand (slot = [256][32] bf16 = 16KB; 128KB).
//   - STAGE AT PHASE TOP: gload_lds issued before ds_reads/MFMA each phase
//     (loads enter the memory system earlier; WAR safe: slot staged at ph p
//     was last ds_read at ph p-2, drained before ph p-1's MFMAs/barrier).
//   - fragment reads pipelined one phase ahead (register double-buffer).
//   - WAIT6 at ODD phases, WAIT8 prologue: each slot is force-landed by the
//     barrier of the phase preceding its first ds_read, with 6-10 loads in
//     flight per wave and 3-4 phases of flight per load (was 2-3 with
//     WAIT4-even). Queue proof in session notes (R2).
//   - swizzle both-sides: linear LDS dest, pre-swizzled global source,
//     same XOR on read side -> 0 bank conflicts (verified R1/R2 PMC).
// ---------------------------------------------------------------------------
#define GK 4096

#define MF(A_, B_, C_) __builtin_amdgcn_mfma_f32_16x16x32_bf16(A_, B_, C_, 0, 0, 0)

#define STAGE_A(SLOT, KC) do {                                              \
    load_lds16(srcA0 + (KC) * 64, ldsA + (SLOT) * 16384 + ldst);            \
    load_lds16(srcA1 + (KC) * 64, ldsA + (SLOT) * 16384 + 8192 + ldst);     \
  } while (0)
#define STAGE_B(SLOT, KC) do {                                              \
    load_lds16(srcB0 + (KC) * 64, ldsB + (SLOT) * 16384 + ldst);            \
    load_lds16(srcB1 + (KC) * 64, ldsB + (SLOT) * 16384 + 8192 + ldst);     \
  } while (0)

#define WAIT6 asm volatile("s_waitcnt vmcnt(6)" ::: "memory")
#define WAIT8 asm volatile("s_waitcnt vmcnt(8)" ::: "memory")
#define VNOP  ((void)0)

#define LDA(S, M) (*(const bf16x8*)(ldsA + (S) * 16384 + (M) * 1024 + aoff))
#define LDB(S, N) (*(const bf16x8*)(ldsB + (S) * 16384 + (N) * 1024 + boff))

#define RD_ALO(S) aA0 = LDA(S, 0); aA1 = LDA(S, 1); aA2 = LDA(S, 2); aA3 = LDA(S, 3)
#define RD_AHI(S) aB0 = LDA(S, 4); aB1 = LDA(S, 5); aB2 = LDA(S, 6); aB3 = LDA(S, 7)
#define RD_BA(S)  bA0 = LDB(S, 0); bA1 = LDB(S, 1); bA2 = LDB(S, 2); bA3 = LDB(S, 3)
#define RD_BB(S)  bB0 = LDB(S, 0); bB1 = LDB(S, 1); bB2 = LDB(S, 2); bB3 = LDB(S, 3)

#define MFMA16(A0, A1, A2, A3, B0, B1, B2, B3, R)                           \
    acc[(R)+0][0] = MF(A0, B0, acc[(R)+0][0]);                              \
    acc[(R)+0][1] = MF(A0, B1, acc[(R)+0][1]);                              \
    acc[(R)+0][2] = MF(A0, B2, acc[(R)+0][2]);                              \
    acc[(R)+0][3] = MF(A0, B3, acc[(R)+0][3]);                              \
    acc[(R)+1][0] = MF(A1, B0, acc[(R)+1][0]);                              \
    acc[(R)+1][1] = MF(A1, B1, acc[(R)+1][1]);                              \
    acc[(R)+1][2] = MF(A1, B2, acc[(R)+1][2]);                              \
    acc[(R)+1][3] = MF(A1, B3, acc[(R)+1][3]);                              \
    acc[(R)+2][0] = MF(A2, B0, acc[(R)+2][0]);                              \
    acc[(R)+2][1] = MF(A2, B1, acc[(R)+2][1]);                              \
    acc[(R)+2][2] = MF(A2, B2, acc[(R)+2][2]);                              \
    acc[(R)+2][3] = MF(A2, B3, acc[(R)+2][3]);                              \
    acc[(R)+3][0] = MF(A3, B0, acc[(R)+3][0]);                              \
    acc[(R)+3][1] = MF(A3, B1, acc[(R)+3][1]);                              \
    acc[(R)+3][2] = MF(A3, B2, acc[(R)+3][2]);                              \
    acc[(R)+3][3] = MF(A3, B3, acc[(R)+3][3]);

#define PHASE(RDNEXT, STG, A0, A1, A2, A3, B0, B1, B2, B3, R, VM)           \
  { STG;                                                                    \
    RDNEXT;                                                                 \
    __builtin_amdgcn_s_setprio(1);                                          \
    MFMA16(A0, A1, A2, A3, B0, B1, B2, B3, R)                               \
    __builtin_amdgcn_s_setprio(0);                                          \
    VM;                                                                     \
    __builtin_amdgcn_s_barrier(); }

__global__ __launch_bounds__(512, 1) void gemm8_k(const u16* __restrict__ A,
                                                  const u16* __restrict__ B,
                                                  const float* __restrict__ bias,
                                                  float* __restrict__ C,
                                                  int M, int N) {
    __shared__ __align__(16) u16 sAq[4 * 256 * 32];   // 64 KB
    __shared__ __align__(16) u16 sBq[4 * 256 * 32];   // 64 KB

    const int tid  = threadIdx.x;
    const int wave = tid >> 6;
    const int lane = tid & 63;

    // XCD-aware bijective block swizzle (nwg % 8 == 0 here: 512)
    const int ntx = N >> 8;
    const int nwg = (M >> 8) * ntx;
    const int cpx = nwg >> 3;
    const int bid = blockIdx.x;
    const int wg  = (bid & 7) * cpx + (bid >> 3);
    const int bm = (wg / ntx) << 8;
    const int bn = (wg % ntx) << 8;

    // ---- staging: per-thread global source (pre-swizzled), linear LDS dest
    const int r4  = tid >> 2;                                  // 0..127
    const int cbs = ((tid & 3) << 4) ^ (((r4 >> 1) & 3) << 4); // swizzled 16B slot
    const char* srcA0 = (const char*)A + ((size_t)(bm + r4) * GK) * 2 + cbs;
    const char* srcA1 = (const char*)A + ((size_t)(bm + 128 + r4) * GK) * 2 + cbs;
    const char* srcB0 = (const char*)B + ((size_t)(bn + r4) * GK) * 2 + cbs;
    const char* srcB1 = (const char*)B + ((size_t)(bn + 128 + r4) * GK) * 2 + cbs;

    char* ldsA = (char*)sAq;
    char* ldsB = (char*)sBq;
    const int ldst = wave << 10;   // wave-uniform 1KB chunk within 8KB half

    // ---- fragment read bases (swizzle independent of m/n -> imm offsets)
    const int frow = lane & 15;
    const int fk2  = (lane >> 4) << 4;          // 16B k-slot
    const int fswz = ((frow >> 1) & 3) << 4;
    const int wmr  = (wave >> 2) << 7;          // 0 / 128
    const int wnr  = (wave & 3) << 6;           // 0 / 64 / 128 / 192
    const int aoff = ((wmr + frow) << 6) + (fk2 ^ fswz);
    const int boff = ((wnr + frow) << 6) + (fk2 ^ fswz);

    f32x4 acc[8][4] = {};
    bf16x8 aA0, aA1, aA2, aA3, aB0, aB1, aB2, aB3;
    bf16x8 bA0, bA1, bA2, bA3, bB0, bB1, bB2, bB3;

    // ---- prologue: stage chunks 0,1,2 into slots 0,1,2 (12 loads);
    //      WAIT8 -> slot0 landed; slots 1,2 + stay in flight.
    STAGE_A(0, 0); STAGE_B(0, 0);
    STAGE_A(1, 1); STAGE_B(1, 1);
    STAGE_A(2, 2); STAGE_B(2, 2);
    WAIT8;
    __builtin_amdgcn_s_barrier();
    RD_ALO(0); RD_BA(0);

    // ---- main loop: 32 iters x 4 k-chunks (k advances 128/iter)
    for (int it = 0; it < 32; ++it) {
        const int c   = it * 4;
        const int kc3 = c + 3;
        const int kc4 = (c + 4) & 127;   // wrap on last iter: harmless refetch
        const int kc5 = (c + 5) & 127;
        const int kc6 = (c + 6) & 127;

        PHASE(RD_AHI(0),            STAGE_A(3, kc3), aA0, aA1, aA2, aA3, bA0, bA1, bA2, bA3, 0, WAIT6)
        PHASE(RD_ALO(1); RD_BB(1),  STAGE_B(3, kc3), aB0, aB1, aB2, aB3, bA0, bA1, bA2, bA3, 4, VNOP)
        PHASE(RD_AHI(1),            STAGE_A(0, kc4), aA0, aA1, aA2, aA3, bB0, bB1, bB2, bB3, 0, WAIT6)
        PHASE(RD_ALO(2); RD_BA(2),  STAGE_B(0, kc4), aB0, aB1, aB2, aB3, bB0, bB1, bB2, bB3, 4, VNOP)
        PHASE(RD_AHI(2),            STAGE_A(1, kc5), aA0, aA1, aA2, aA3, bA0, bA1, bA2, bA3, 0, WAIT6)
        PHASE(RD_ALO(3); RD_BB(3),  STAGE_B(1, kc5), aB0, aB1, aB2, aB3, bA0, bA1, bA2, bA3, 4, VNOP)
        PHASE(RD_AHI(3),            STAGE_A(2, kc6), aA0, aA1, aA2, aA3, bB0, bB1, bB2, bB3, 0, WAIT6)
        PHASE(RD_ALO(0); RD_BA(0),  STAGE_B(2, kc6), aB0, aB1, aB2, aB3, bB0, bB1, bB2, bB3, 4, VNOP)
    }

    // ---- epilogue: C = acc + bias
    const int cm = bm + wmr;
    const int cn = bn + wnr;
#pragma unroll
    for (int n = 0; n < 4; ++n) {
        const int col = cn + n * 16 + frow;
        const float bv = bias[col];
#pragma unroll
        for (int m = 0; m < 8; ++m) {
            const int r0 = cm + m * 16 + (lane >> 4) * 4;
#pragma unroll
            for (int r = 0; r < 4; ++r)
                C[(size_t)(r0 + r) * N + col] = acc[m][n][r] + bv;
        }
    }
}

// ---------------------------------------------------------------------------
extern "C" void kernel_launch(void* const* d_in, const int* in_sizes, int n_in,
                              void* d_out, int out_size, void* d_ws, size_t ws_size,
                              hipStream_t stream) {
    (void)n_in; (void)out_size; (void)ws_size;
    const float* x     = (const float*)d_in[0];
    const float* lut   = (const float*)d_in[1];
    const float* bias  = (const float*)d_in[2];
    const float* ovals = (const float*)d_in[3];
    const int*   qw    = (const int*)d_in[4];
    const int*   orows = (const int*)d_in[5];
    const int*   ocols = (const int*)d_in[6];
    float* y = (float*)d_out;

    const int M = in_sizes[0] / IN_F;   // 8192

    u16* W  = (u16*)d_ws;                                        // 32 MB
    u16* xb = (u16*)((char*)d_ws + (size_t)OUT_F * IN_F * 2);    // 64 MB

    const int cvt_blocks = (int)((size_t)M * IN_F / 8 / 256);    // 16384
    prep_k<<<DQ_BLOCKS + cvt_blocks, 256, 0, stream>>>(
        qw, lut, orows, ocols, ovals, W, (const float4*)x, xb);

    const int nwg = (M / 256) * (OUT_F / 256);                   // 512
    gemm8_k<<<dim3(nwg), dim3(512), 0, stream>>>(xb, W, bias, y, M, OUT_F);
}